// Round 1
// baseline (189.597 us; speedup 1.0000x reference)
//
#include <hip/hip_runtime.h>
#include <hip/hip_bf16.h>
#include <stdint.h>

// RelMHAtt: B=4 S=512 HIDDEN=1024 H=16 D=64 R=64
// Pipeline: convert(fp32->bf16) -> proj GEMM (q scaled 1/8, v transposed) ->
//           rel bias (log(clip(relu(rel@Wr.T+br))) as bf16 [B,H,S,S]) ->
//           attention (bias-preload + QK^T += , softmax, PV) -> out GEMM fp32.

typedef __attribute__((ext_vector_type(8))) short bf16x8;
typedef __attribute__((ext_vector_type(4))) float f32x4;

__device__ inline unsigned short f2bf(float f) {
    __hip_bfloat16 h = __float2bfloat16(f);
    return *reinterpret_cast<unsigned short*>(&h);
}
__device__ inline float bf2f(unsigned short u) {
    unsigned int t = ((unsigned int)u) << 16;
    return __builtin_bit_cast(float, t);
}

// ---------------------------------------------------------------- convert
// dst layout (bf16): xq[2M] xk[2M] xv[2M] Wq[1M] Wk[1M] Wv[1M] Wm[1M]
__global__ __launch_bounds__(256) void convert_kernel(
    const float* __restrict__ q, const float* __restrict__ k, const float* __restrict__ v,
    const float* __restrict__ wq, const float* __restrict__ wk, const float* __restrict__ wv,
    const float* __restrict__ wm, unsigned short* __restrict__ dst)
{
    const long long X = 2097152LL, Wn = 1048576LL;
    long long e = 4LL * ((long long)blockIdx.x * 256 + threadIdx.x);
    const float* s;
    long long o = e;
    if      (o < X)          { s = q; }
    else if (o < 2*X)        { s = k;  o -= X; }
    else if (o < 3*X)        { s = v;  o -= 2*X; }
    else if (o < 3*X + Wn)   { s = wq; o -= 3*X; }
    else if (o < 3*X + 2*Wn) { s = wk; o -= 3*X + Wn; }
    else if (o < 3*X + 3*Wn) { s = wv; o -= 3*X + 2*Wn; }
    else                     { s = wm; o -= 3*X + 3*Wn; }
    float4 val = *reinterpret_cast<const float4*>(s + o);
    ushort4 u;
    u.x = f2bf(val.x); u.y = f2bf(val.y); u.z = f2bf(val.z); u.w = f2bf(val.w);
    *reinterpret_cast<ushort4*>(dst + e) = u;
}

// ---------------------------------------------------------------- GEMM
// C[m,n] = sum_k A[m,k]*B[n,k] + bias[n];  A[M,1024], B[1024,1024] bf16.
// mode 0: f32 store [M,1024]       (final proj, C=d_out)
// mode 1: bf16 store [M,1024]      (k proj)
// mode 2: bf16 store *0.125        (q proj, folds 1/sqrt(64))
// mode 3: bf16 store transposed vht[b][h][d][s]   (v proj)
struct GemmJob { const unsigned short* A; const unsigned short* B; const float* bias; char* C; int mode; };
struct Gemm3 { GemmJob j[3]; };

__global__ __launch_bounds__(256) void gemm_bt(Gemm3 g)
{
    GemmJob jb = g.j[blockIdx.z];
    const unsigned short* __restrict__ A = jb.A;
    const unsigned short* __restrict__ B = jb.B;
    __shared__ alignas(16) unsigned short As[2][4096];   // [128][32] bf16 per buf
    __shared__ alignas(16) unsigned short Bs[2][4096];
    int tid = threadIdx.x;
    int bm0 = blockIdx.x * 128, bn0 = blockIdx.y * 128;
    int wid = tid >> 6, lane = tid & 63;
    int fr = lane & 15, fq = lane >> 4;
    int wm = (wid >> 1) * 64, wn = (wid & 1) * 64;

    f32x4 acc[4][4];
    f32x4 z4 = {0.f, 0.f, 0.f, 0.f};
    for (int i = 0; i < 4; i++) for (int j = 0; j < 4; j++) acc[i][j] = z4;

    auto stage = [&](int buf, int kt) {
        #pragma unroll
        for (int i = 0; i < 2; i++) {
            int ci = tid + 256 * i;
            int row = ci >> 2, kc = ci & 3;
            const unsigned short* ga = A + (long long)(bm0 + row) * 1024 + kt * 32 + kc * 8;
            __builtin_amdgcn_global_load_lds((const __attribute__((address_space(1))) void*)ga,
                (__attribute__((address_space(3))) void*)(&As[buf][ci * 8]), 16, 0, 0);
            const unsigned short* gb = B + (long long)(bn0 + row) * 1024 + kt * 32 + kc * 8;
            __builtin_amdgcn_global_load_lds((const __attribute__((address_space(1))) void*)gb,
                (__attribute__((address_space(3))) void*)(&Bs[buf][ci * 8]), 16, 0, 0);
        }
    };
    auto compute = [&](int buf) {
        bf16x8 a[4], b[4];
        #pragma unroll
        for (int fm = 0; fm < 4; fm++)
            a[fm] = *reinterpret_cast<const bf16x8*>(&As[buf][(wm + fm*16 + fr)*32 + fq*8]);
        #pragma unroll
        for (int fn = 0; fn < 4; fn++)
            b[fn] = *reinterpret_cast<const bf16x8*>(&Bs[buf][(wn + fn*16 + fr)*32 + fq*8]);
        #pragma unroll
        for (int fm = 0; fm < 4; fm++)
            #pragma unroll
            for (int fn = 0; fn < 4; fn++)
                acc[fm][fn] = __builtin_amdgcn_mfma_f32_16x16x32_bf16(a[fm], b[fn], acc[fm][fn], 0, 0, 0);
    };

    stage(0, 0);
    asm volatile("s_waitcnt vmcnt(0)" ::: "memory");
    __syncthreads();
    int cur = 0;
    for (int kt = 0; kt < 31; kt++) {
        stage(cur ^ 1, kt + 1);
        compute(cur);
        asm volatile("s_waitcnt vmcnt(0)" ::: "memory");
        __syncthreads();
        cur ^= 1;
    }
    compute(cur);

    int mode = jb.mode;
    #pragma unroll
    for (int fm = 0; fm < 4; fm++) {
        #pragma unroll
        for (int fn = 0; fn < 4; fn++) {
            int col = bn0 + wn + fn*16 + fr;
            float bv = jb.bias[col];
            f32x4 vacc = acc[fm][fn];
            #pragma unroll
            for (int r = 0; r < 4; r++) {
                int m = bm0 + wm + fm*16 + fq*4 + r;
                float val = vacc[r] + bv;
                if (mode == 0) {
                    reinterpret_cast<float*>(jb.C)[(long long)m*1024 + col] = val;
                } else if (mode == 1) {
                    reinterpret_cast<unsigned short*>(jb.C)[(long long)m*1024 + col] = f2bf(val);
                } else if (mode == 2) {
                    reinterpret_cast<unsigned short*>(jb.C)[(long long)m*1024 + col] = f2bf(val * 0.125f);
                } else {
                    int bb = m >> 9, ss = m & 511;
                    int hh = col >> 6, dd = col & 63;
                    reinterpret_cast<unsigned short*>(jb.C)[(((long long)bb*16 + hh)*64 + dd)*512 + ss] = f2bf(val);
                }
            }
        }
    }
}

// ---------------------------------------------------------------- rel bias
// biasOut[b][h][q][k] = log(max(dot(rel[b,q,k,:], Wr[h,:]) + br[h], 1e-6)) as bf16
__global__ __launch_bounds__(256) void rel_kernel(
    const float* __restrict__ rel, const float* __restrict__ Wr, const float* __restrict__ br,
    unsigned short* __restrict__ biasOut)
{
    __shared__ alignas(16) float rl[64][72];   // pad 72 -> ~2-way banks on b128
    __shared__ alignas(16) float wr[16][64];
    __shared__ float brs[16];
    int tid = threadIdx.x;
    int k0 = blockIdx.x * 64;
    int q  = blockIdx.y;
    int b  = blockIdx.z;
    const float* gsrc = rel + ((long long)(b*512 + q)*512 + k0) * 64;
    #pragma unroll
    for (int i = 0; i < 4; i++) {
        int ci = tid + 256*i;
        int row = ci >> 4, c4 = ci & 15;
        float4 v4 = *reinterpret_cast<const float4*>(gsrc + row*64 + c4*4);
        *reinterpret_cast<float4*>(&rl[row][c4*4]) = v4;
    }
    {
        int row = tid >> 4, c4 = tid & 15;
        *reinterpret_cast<float4*>(&wr[row][c4*4]) =
            *reinterpret_cast<const float4*>(Wr + row*64 + c4*4);
        if (tid < 16) brs[tid] = br[tid];
    }
    __syncthreads();
    int k = tid & 63, h0 = (tid >> 6) * 4;
    float a0 = brs[h0], a1 = brs[h0+1], a2 = brs[h0+2], a3 = brs[h0+3];
    #pragma unroll
    for (int c4 = 0; c4 < 16; c4++) {
        float4 r4 = *reinterpret_cast<const float4*>(&rl[k][c4*4]);
        float4 w0 = *reinterpret_cast<const float4*>(&wr[h0  ][c4*4]);
        float4 w1 = *reinterpret_cast<const float4*>(&wr[h0+1][c4*4]);
        float4 w2 = *reinterpret_cast<const float4*>(&wr[h0+2][c4*4]);
        float4 w3 = *reinterpret_cast<const float4*>(&wr[h0+3][c4*4]);
        a0 += r4.x*w0.x + r4.y*w0.y + r4.z*w0.z + r4.w*w0.w;
        a1 += r4.x*w1.x + r4.y*w1.y + r4.z*w1.z + r4.w*w1.w;
        a2 += r4.x*w2.x + r4.y*w2.y + r4.z*w2.z + r4.w*w2.w;
        a3 += r4.x*w3.x + r4.y*w3.y + r4.z*w3.z + r4.w*w3.w;
    }
    long long base = ((long long)(b*16 + h0)*512 + q)*512 + k0 + k;
    const long long HS = 512LL*512LL;
    biasOut[base       ] = f2bf(__logf(fmaxf(a0, 1e-6f)));
    biasOut[base +   HS] = f2bf(__logf(fmaxf(a1, 1e-6f)));
    biasOut[base + 2*HS] = f2bf(__logf(fmaxf(a2, 1e-6f)));
    biasOut[base + 3*HS] = f2bf(__logf(fmaxf(a3, 1e-6f)));
}

// ---------------------------------------------------------------- attention
// per block: (b, h, 16 q-rows). sc preloaded with bias(+mask), QK^T added on top,
// wave-parallel softmax, PV with vht (V transposed) read straight from global.
__global__ __launch_bounds__(256) void attn_kernel(
    const unsigned short* __restrict__ qh, const unsigned short* __restrict__ kh,
    const unsigned short* __restrict__ vht, const unsigned short* __restrict__ biasT,
    const unsigned char* __restrict__ mask, unsigned short* __restrict__ atted)
{
    __shared__ alignas(16) float sc[16][516];
    __shared__ alignas(16) unsigned short P[16][520];
    __shared__ float rowsum[16];
    int tid = threadIdx.x;
    int wid = tid >> 6, lane = tid & 63;
    int fr = lane & 15, fq = lane >> 4;
    int q0 = blockIdx.x * 16;
    int h = blockIdx.y, b = blockIdx.z;

    // Q fragments (q already scaled by 1/8 at projection)
    bf16x8 aq[2];
    #pragma unroll
    for (int df = 0; df < 2; df++)
        aq[df] = *reinterpret_cast<const bf16x8*>(
            qh + (long long)(b*512 + q0 + fr)*1024 + h*64 + df*32 + fq*8);

    // bias + mask preload into sc
    const unsigned short* bb = biasT + ((long long)(b*16 + h)*512 + q0)*512;
    #pragma unroll
    for (int i = 0; i < 4; i++) {
        int ci = tid + 256*i;
        int row = ci >> 6, c8 = ci & 63;
        bf16x8 bv8 = *reinterpret_cast<const bf16x8*>(bb + row*512 + c8*8);
        unsigned long long mb = *reinterpret_cast<const unsigned long long*>(mask + b*512 + c8*8);
        #pragma unroll
        for (int j = 0; j < 8; j++) {
            float val = bf2f((unsigned short)bv8[j]);
            if ((mb >> (8*j)) & 0xffULL) val = -1e9f;
            sc[row][c8*8 + j] = val;
        }
    }
    __syncthreads();

    // pass 1: QK^T accumulate into sc
    for (int c = wid; c < 16; c += 4) {
        int kbase = c * 32;
        f32x4 accs0 = {0.f,0.f,0.f,0.f}, accs1 = {0.f,0.f,0.f,0.f};
        #pragma unroll
        for (int df = 0; df < 2; df++) {
            bf16x8 bk0 = *reinterpret_cast<const bf16x8*>(
                kh + (long long)(b*512 + kbase + fr)*1024 + h*64 + df*32 + fq*8);
            bf16x8 bk1 = *reinterpret_cast<const bf16x8*>(
                kh + (long long)(b*512 + kbase + 16 + fr)*1024 + h*64 + df*32 + fq*8);
            accs0 = __builtin_amdgcn_mfma_f32_16x16x32_bf16(aq[df], bk0, accs0, 0, 0, 0);
            accs1 = __builtin_amdgcn_mfma_f32_16x16x32_bf16(aq[df], bk1, accs1, 0, 0, 0);
        }
        #pragma unroll
        for (int r = 0; r < 4; r++) {
            sc[fq*4 + r][kbase + fr]      += accs0[r];
            sc[fq*4 + r][kbase + 16 + fr] += accs1[r];
        }
    }
    __syncthreads();

    // softmax: wave wid owns rows wid*4 .. wid*4+3
    #pragma unroll
    for (int rr = 0; rr < 4; rr++) {
        int row = wid*4 + rr;
        float vals[8];
        float m = -3e38f;
        #pragma unroll
        for (int i = 0; i < 8; i++) { vals[i] = sc[row][lane + 64*i]; m = fmaxf(m, vals[i]); }
        #pragma unroll
        for (int s = 1; s < 64; s <<= 1) m = fmaxf(m, __shfl_xor(m, s, 64));
        float sum = 0.f;
        #pragma unroll
        for (int i = 0; i < 8; i++) {
            float p = __expf(vals[i] - m);
            sum += p;
            P[row][lane + 64*i] = f2bf(p);
        }
        #pragma unroll
        for (int s = 1; s < 64; s <<= 1) sum += __shfl_xor(sum, s, 64);
        if (lane == 0) rowsum[row] = sum;
    }
    __syncthreads();

    // pass 2: PV. wave wid owns d-slice [wid*16, wid*16+16)
    int d0 = wid * 16;
    f32x4 acco = {0.f,0.f,0.f,0.f};
    for (int c = 0; c < 16; c++) {
        bf16x8 pa = *reinterpret_cast<const bf16x8*>(&P[fr][c*32 + fq*8]);
        bf16x8 bv = *reinterpret_cast<const bf16x8*>(
            vht + ((long long)(b*16 + h)*64 + d0 + fr)*512 + c*32 + fq*8);
        acco = __builtin_amdgcn_mfma_f32_16x16x32_bf16(pa, bv, acco, 0, 0, 0);
    }
    #pragma unroll
    for (int r = 0; r < 4; r++) {
        int row = fq*4 + r;
        float val = acco[r] / rowsum[row];
        atted[(long long)(b*512 + q0 + row)*1024 + h*64 + d0 + fr] = f2bf(val);
    }
}

// ---------------------------------------------------------------- launch
extern "C" void kernel_launch(void* const* d_in, const int* in_sizes, int n_in,
                              void* d_out, int out_size, void* d_ws, size_t ws_size,
                              hipStream_t stream)
{
    const float* v    = (const float*)d_in[0];
    const float* k    = (const float*)d_in[1];
    const float* q    = (const float*)d_in[2];
    const unsigned char* mask = (const unsigned char*)d_in[3];
    const float* rel  = (const float*)d_in[4];
    const float* Wv   = (const float*)d_in[5];
    const float* bv   = (const float*)d_in[6];
    const float* Wk   = (const float*)d_in[7];
    const float* bk   = (const float*)d_in[8];
    const float* Wq   = (const float*)d_in[9];
    const float* bq   = (const float*)d_in[10];
    const float* Wr   = (const float*)d_in[11];
    const float* br   = (const float*)d_in[12];
    const float* Wm   = (const float*)d_in[13];
    const float* bm   = (const float*)d_in[14];

    const long long MB = 1 << 20;
    char* W = (char*)d_ws;
    unsigned short* xq    = (unsigned short*)(W + 0*MB);
    unsigned short* xk    = (unsigned short*)(W + 4*MB);
    unsigned short* xv    = (unsigned short*)(W + 8*MB);
    unsigned short* Wqb   = (unsigned short*)(W + 12*MB);
    unsigned short* Wkb   = (unsigned short*)(W + 14*MB);
    unsigned short* Wvb   = (unsigned short*)(W + 16*MB);
    unsigned short* Wmb   = (unsigned short*)(W + 18*MB);
    unsigned short* qhb   = (unsigned short*)(W + 20*MB);
    unsigned short* khb   = (unsigned short*)(W + 24*MB);
    unsigned short* vht   = (unsigned short*)(W + 28*MB);
    unsigned short* atted = (unsigned short*)(W + 32*MB);
    unsigned short* biasT = (unsigned short*)(W + 36*MB);  // 32 MB

    convert_kernel<<<10240, 256, 0, stream>>>(q, k, v, Wq, Wk, Wv, Wm, (unsigned short*)W);

    Gemm3 gp;
    gp.j[0] = { xq, Wqb, bq, (char*)qhb, 2 };
    gp.j[1] = { xk, Wkb, bk, (char*)khb, 1 };
    gp.j[2] = { xv, Wvb, bv, (char*)vht, 3 };
    gemm_bt<<<dim3(16, 8, 3), 256, 0, stream>>>(gp);

    rel_kernel<<<dim3(8, 512, 4), 256, 0, stream>>>(rel, Wr, br, biasT);

    attn_kernel<<<dim3(32, 16, 4), 256, 0, stream>>>(qhb, khb, vht, biasT, mask, atted);

    Gemm3 gf;
    gf.j[0] = { atted, Wmb, bm, (char*)d_out, 0 };
    gf.j[1] = gf.j[0];
    gf.j[2] = gf.j[0];
    gemm_bt<<<dim3(16, 8, 1), 256, 0, stream>>>(gf);
}

// Round 2
// 175.192 us; speedup vs baseline: 1.0822x; 1.0822x over previous
//
#include <hip/hip_runtime.h>
#include <hip/hip_bf16.h>
#include <stdint.h>

// RelMHAtt: B=4 S=512 HIDDEN=1024 H=16 D=64 R=64
// Pipeline: convert(fp32->bf16) -> proj GEMM (q scaled 1/8, v transposed) ->
//           rel bias (log(clip(relu(rel@Wr.T+br))) as bf16 [B,H,S,S]) ->
//           attention (register scores + frag-layout bias add, reg softmax) ->
//           out GEMM fp32.

typedef __attribute__((ext_vector_type(8))) short bf16x8;
typedef __attribute__((ext_vector_type(4))) float f32x4;

__device__ inline unsigned short f2bf(float f) {
    __hip_bfloat16 h = __float2bfloat16(f);
    return *reinterpret_cast<unsigned short*>(&h);
}
__device__ inline float bf2f(unsigned short u) {
    unsigned int t = ((unsigned int)u) << 16;
    return __builtin_bit_cast(float, t);
}

// ---------------------------------------------------------------- convert
// dst layout (bf16): xq[2M] xk[2M] xv[2M] Wq[1M] Wk[1M] Wv[1M] Wm[1M]
__global__ __launch_bounds__(256) void convert_kernel(
    const float* __restrict__ q, const float* __restrict__ k, const float* __restrict__ v,
    const float* __restrict__ wq, const float* __restrict__ wk, const float* __restrict__ wv,
    const float* __restrict__ wm, unsigned short* __restrict__ dst)
{
    const long long X = 2097152LL, Wn = 1048576LL;
    long long e = 4LL * ((long long)blockIdx.x * 256 + threadIdx.x);
    const float* s;
    long long o = e;
    if      (o < X)          { s = q; }
    else if (o < 2*X)        { s = k;  o -= X; }
    else if (o < 3*X)        { s = v;  o -= 2*X; }
    else if (o < 3*X + Wn)   { s = wq; o -= 3*X; }
    else if (o < 3*X + 2*Wn) { s = wk; o -= 3*X + Wn; }
    else if (o < 3*X + 3*Wn) { s = wv; o -= 3*X + 2*Wn; }
    else                     { s = wm; o -= 3*X + 3*Wn; }
    float4 val = *reinterpret_cast<const float4*>(s + o);
    ushort4 u;
    u.x = f2bf(val.x); u.y = f2bf(val.y); u.z = f2bf(val.z); u.w = f2bf(val.w);
    *reinterpret_cast<ushort4*>(dst + e) = u;
}

// ---------------------------------------------------------------- GEMM
// C[m,n] = sum_k A[m,k]*B[n,k] + bias[n];  A[M,1024], B[1024,1024] bf16.
// BM=64, BN=128, BK=32; 4 waves, each 32x64.
// mode 0: f32 store [M,1024]       (final proj, C=d_out)
// mode 1: bf16 store [M,1024]      (k proj)
// mode 2: bf16 store *0.125        (q proj, folds 1/sqrt(64))
// mode 3: bf16 store transposed vht[b][h][d][s]   (v proj)
struct GemmJob { const unsigned short* A; const unsigned short* B; const float* bias; char* C; int mode; };
struct Gemm3 { GemmJob j[3]; };

__global__ __launch_bounds__(256) void gemm_bt(Gemm3 g)
{
    GemmJob jb = g.j[blockIdx.z];
    const unsigned short* __restrict__ A = jb.A;
    const unsigned short* __restrict__ B = jb.B;
    __shared__ alignas(16) unsigned short As[2][2048];   // [64][32] bf16 per buf
    __shared__ alignas(16) unsigned short Bs[2][4096];   // [128][32]
    int tid = threadIdx.x;
    int bm0 = blockIdx.x * 64, bn0 = blockIdx.y * 128;
    int wid = tid >> 6, lane = tid & 63;
    int fr = lane & 15, fq = lane >> 4;
    int wm = (wid >> 1) * 32, wn = (wid & 1) * 64;

    f32x4 acc[2][4];
    f32x4 z4 = {0.f, 0.f, 0.f, 0.f};
    for (int i = 0; i < 2; i++) for (int j = 0; j < 4; j++) acc[i][j] = z4;

    auto stage = [&](int buf, int kt) {
        {
            int ci = tid;
            int row = ci >> 2, kc = ci & 3;
            const unsigned short* ga = A + (long long)(bm0 + row) * 1024 + kt * 32 + kc * 8;
            __builtin_amdgcn_global_load_lds((const __attribute__((address_space(1))) void*)ga,
                (__attribute__((address_space(3))) void*)(&As[buf][ci * 8]), 16, 0, 0);
        }
        #pragma unroll
        for (int i = 0; i < 2; i++) {
            int ci = tid + 256 * i;
            int row = ci >> 2, kc = ci & 3;
            const unsigned short* gb = B + (long long)(bn0 + row) * 1024 + kt * 32 + kc * 8;
            __builtin_amdgcn_global_load_lds((const __attribute__((address_space(1))) void*)gb,
                (__attribute__((address_space(3))) void*)(&Bs[buf][ci * 8]), 16, 0, 0);
        }
    };
    auto compute = [&](int buf) {
        bf16x8 a[2], b[4];
        #pragma unroll
        for (int fm = 0; fm < 2; fm++)
            a[fm] = *reinterpret_cast<const bf16x8*>(&As[buf][(wm + fm*16 + fr)*32 + fq*8]);
        #pragma unroll
        for (int fn = 0; fn < 4; fn++)
            b[fn] = *reinterpret_cast<const bf16x8*>(&Bs[buf][(wn + fn*16 + fr)*32 + fq*8]);
        #pragma unroll
        for (int fm = 0; fm < 2; fm++)
            #pragma unroll
            for (int fn = 0; fn < 4; fn++)
                acc[fm][fn] = __builtin_amdgcn_mfma_f32_16x16x32_bf16(a[fm], b[fn], acc[fm][fn], 0, 0, 0);
    };

    stage(0, 0);
    asm volatile("s_waitcnt vmcnt(0)" ::: "memory");
    __syncthreads();
    int cur = 0;
    for (int kt = 0; kt < 31; kt++) {
        stage(cur ^ 1, kt + 1);
        compute(cur);
        asm volatile("s_waitcnt vmcnt(0)" ::: "memory");
        __syncthreads();
        cur ^= 1;
    }
    compute(cur);

    int mode = jb.mode;
    #pragma unroll
    for (int fm = 0; fm < 2; fm++) {
        #pragma unroll
        for (int fn = 0; fn < 4; fn++) {
            int col = bn0 + wn + fn*16 + fr;
            float bv = jb.bias[col];
            f32x4 vacc = acc[fm][fn];
            #pragma unroll
            for (int r = 0; r < 4; r++) {
                int m = bm0 + wm + fm*16 + fq*4 + r;
                float val = vacc[r] + bv;
                if (mode == 0) {
                    reinterpret_cast<float*>(jb.C)[(long long)m*1024 + col] = val;
                } else if (mode == 1) {
                    reinterpret_cast<unsigned short*>(jb.C)[(long long)m*1024 + col] = f2bf(val);
                } else if (mode == 2) {
                    reinterpret_cast<unsigned short*>(jb.C)[(long long)m*1024 + col] = f2bf(val * 0.125f);
                } else {
                    int bb = m >> 9, ss = m & 511;
                    int hh = col >> 6, dd = col & 63;
                    reinterpret_cast<unsigned short*>(jb.C)[(((long long)bb*16 + hh)*64 + dd)*512 + ss] = f2bf(val);
                }
            }
        }
    }
}

// ---------------------------------------------------------------- rel bias
// biasOut[b][h][q][k] = log(max(dot(rel[b,q,k,:], Wr[h,:]) + br[h], 1e-6)) as bf16
__global__ __launch_bounds__(256) void rel_kernel(
    const float* __restrict__ rel, const float* __restrict__ Wr, const float* __restrict__ br,
    unsigned short* __restrict__ biasOut)
{
    __shared__ alignas(16) float rl[64][72];
    __shared__ alignas(16) float wr[16][64];
    __shared__ float brs[16];
    int tid = threadIdx.x;
    int k0 = blockIdx.x * 64;
    int q  = blockIdx.y;
    int b  = blockIdx.z;
    const float* gsrc = rel + ((long long)(b*512 + q)*512 + k0) * 64;
    #pragma unroll
    for (int i = 0; i < 4; i++) {
        int ci = tid + 256*i;
        int row = ci >> 4, c4 = ci & 15;
        float4 v4 = *reinterpret_cast<const float4*>(gsrc + row*64 + c4*4);
        *reinterpret_cast<float4*>(&rl[row][c4*4]) = v4;
    }
    {
        int row = tid >> 4, c4 = tid & 15;
        *reinterpret_cast<float4*>(&wr[row][c4*4]) =
            *reinterpret_cast<const float4*>(Wr + row*64 + c4*4);
        if (tid < 16) brs[tid] = br[tid];
    }
    __syncthreads();
    int k = tid & 63, h0 = (tid >> 6) * 4;
    float a0 = brs[h0], a1 = brs[h0+1], a2 = brs[h0+2], a3 = brs[h0+3];
    #pragma unroll
    for (int c4 = 0; c4 < 16; c4++) {
        float4 r4 = *reinterpret_cast<const float4*>(&rl[k][c4*4]);
        float4 w0 = *reinterpret_cast<const float4*>(&wr[h0  ][c4*4]);
        float4 w1 = *reinterpret_cast<const float4*>(&wr[h0+1][c4*4]);
        float4 w2 = *reinterpret_cast<const float4*>(&wr[h0+2][c4*4]);
        float4 w3 = *reinterpret_cast<const float4*>(&wr[h0+3][c4*4]);
        a0 += r4.x*w0.x + r4.y*w0.y + r4.z*w0.z + r4.w*w0.w;
        a1 += r4.x*w1.x + r4.y*w1.y + r4.z*w1.z + r4.w*w1.w;
        a2 += r4.x*w2.x + r4.y*w2.y + r4.z*w2.z + r4.w*w2.w;
        a3 += r4.x*w3.x + r4.y*w3.y + r4.z*w3.z + r4.w*w3.w;
    }
    long long base = ((long long)(b*16 + h0)*512 + q)*512 + k0 + k;
    const long long HS = 512LL*512LL;
    biasOut[base       ] = f2bf(__logf(fmaxf(a0, 1e-6f)));
    biasOut[base +   HS] = f2bf(__logf(fmaxf(a1, 1e-6f)));
    biasOut[base + 2*HS] = f2bf(__logf(fmaxf(a2, 1e-6f)));
    biasOut[base + 3*HS] = f2bf(__logf(fmaxf(a3, 1e-6f)));
}

// ---------------------------------------------------------------- attention
// per block: (b, h, 16 q-rows), 4 waves. Scores held in registers:
// wave wid owns cols [wid*128, wid*128+128) as 8 MFMA C-fragments.
// Bias+mask added per-fragment; softmax via in-reg + shfl + 4x16 LDS combine.
// P transposed through LDS (bf16) for the PV A-operand.
__global__ __launch_bounds__(256) void attn_kernel(
    const unsigned short* __restrict__ qh, const unsigned short* __restrict__ kh,
    const unsigned short* __restrict__ vht, const unsigned short* __restrict__ biasT,
    const unsigned char* __restrict__ mask, unsigned short* __restrict__ atted)
{
    __shared__ alignas(16) unsigned short Pl[16][520];
    __shared__ float pmax[4][16];
    __shared__ float psum[4][16];
    int tid = threadIdx.x;
    int wid = tid >> 6, lane = tid & 63;
    int fr = lane & 15, fq = lane >> 4;
    int q0 = blockIdx.x * 16;
    int h = blockIdx.y, b = blockIdx.z;

    // Q fragments (q already scaled by 1/8 at projection). A-row = fr.
    bf16x8 aq[2];
    #pragma unroll
    for (int df = 0; df < 2; df++)
        aq[df] = *reinterpret_cast<const bf16x8*>(
            qh + (long long)(b*512 + q0 + fr)*1024 + h*64 + df*32 + fq*8);

    // QK^T into registers: 8 col-tiles of 16
    f32x4 s[8];
    #pragma unroll
    for (int kt = 0; kt < 8; kt++) {
        int cb = wid*128 + kt*16;
        f32x4 a4 = {0.f,0.f,0.f,0.f};
        #pragma unroll
        for (int df = 0; df < 2; df++) {
            bf16x8 bk = *reinterpret_cast<const bf16x8*>(
                kh + (long long)(b*512 + cb + fr)*1024 + h*64 + df*32 + fq*8);
            a4 = __builtin_amdgcn_mfma_f32_16x16x32_bf16(aq[df], bk, a4, 0, 0, 0);
        }
        s[kt] = a4;
    }

    // bias + mask, fragment layout: col = fr, row = fq*4+r
    const unsigned short* bbase = biasT + ((long long)(b*16 + h)*512 + q0)*512;
    #pragma unroll
    for (int kt = 0; kt < 8; kt++) {
        int col = wid*128 + kt*16 + fr;
        bool mk = mask[b*512 + col] != 0;
        #pragma unroll
        for (int r = 0; r < 4; r++) {
            float bias = bf2f(bbase[(fq*4 + r)*512 + col]);
            float val = s[kt][r] + bias;
            s[kt][r] = mk ? -1e9f : val;
        }
    }

    // row max: in-reg over kt, then 16-lane shfl, then cross-wave LDS
    float rm[4];
    #pragma unroll
    for (int r = 0; r < 4; r++) {
        float m = s[0][r];
        #pragma unroll
        for (int kt = 1; kt < 8; kt++) m = fmaxf(m, s[kt][r]);
        #pragma unroll
        for (int x = 1; x < 16; x <<= 1) m = fmaxf(m, __shfl_xor(m, x, 64));
        rm[r] = m;
    }
    #pragma unroll
    for (int r = 0; r < 4; r++)
        if (fr == r) pmax[wid][fq*4 + r] = rm[r];
    __syncthreads();
    #pragma unroll
    for (int r = 0; r < 4; r++) {
        float m = pmax[0][fq*4 + r];
        m = fmaxf(m, pmax[1][fq*4 + r]);
        m = fmaxf(m, pmax[2][fq*4 + r]);
        m = fmaxf(m, pmax[3][fq*4 + r]);
        rm[r] = m;
    }

    // exp, P write (bf16), row sums
    float sum[4] = {0.f, 0.f, 0.f, 0.f};
    #pragma unroll
    for (int kt = 0; kt < 8; kt++) {
        int col = wid*128 + kt*16 + fr;
        #pragma unroll
        for (int r = 0; r < 4; r++) {
            float p = __expf(s[kt][r] - rm[r]);
            sum[r] += p;
            Pl[fq*4 + r][col] = f2bf(p);
        }
    }
    #pragma unroll
    for (int r = 0; r < 4; r++) {
        float sv = sum[r];
        #pragma unroll
        for (int x = 1; x < 16; x <<= 1) sv += __shfl_xor(sv, x, 64);
        sum[r] = sv;
    }
    #pragma unroll
    for (int r = 0; r < 4; r++)
        if (fr == r) psum[wid][fq*4 + r] = sum[r];
    __syncthreads();
    float sumr[4];
    #pragma unroll
    for (int r = 0; r < 4; r++)
        sumr[r] = psum[0][fq*4+r] + psum[1][fq*4+r] + psum[2][fq*4+r] + psum[3][fq*4+r];

    // PV: wave wid owns d-slice [wid*16, wid*16+16)
    int d0 = wid * 16;
    f32x4 acco = {0.f,0.f,0.f,0.f};
    for (int c = 0; c < 16; c++) {
        bf16x8 pa = *reinterpret_cast<const bf16x8*>(&Pl[fr][c*32 + fq*8]);
        bf16x8 bv = *reinterpret_cast<const bf16x8*>(
            vht + ((long long)(b*16 + h)*64 + d0 + fr)*512 + c*32 + fq*8);
        acco = __builtin_amdgcn_mfma_f32_16x16x32_bf16(pa, bv, acco, 0, 0, 0);
    }
    #pragma unroll
    for (int r = 0; r < 4; r++) {
        float val = acco[r] / sumr[r];
        atted[(long long)(b*512 + q0 + fq*4 + r)*1024 + h*64 + d0 + fr] = f2bf(val);
    }
}

// ---------------------------------------------------------------- launch
extern "C" void kernel_launch(void* const* d_in, const int* in_sizes, int n_in,
                              void* d_out, int out_size, void* d_ws, size_t ws_size,
                              hipStream_t stream)
{
    const float* v    = (const float*)d_in[0];
    const float* k    = (const float*)d_in[1];
    const float* q    = (const float*)d_in[2];
    const unsigned char* mask = (const unsigned char*)d_in[3];
    const float* rel  = (const float*)d_in[4];
    const float* Wv   = (const float*)d_in[5];
    const float* bv   = (const float*)d_in[6];
    const float* Wk   = (const float*)d_in[7];
    const float* bk   = (const float*)d_in[8];
    const float* Wq   = (const float*)d_in[9];
    const float* bq   = (const float*)d_in[10];
    const float* Wr   = (const float*)d_in[11];
    const float* br   = (const float*)d_in[12];
    const float* Wm   = (const float*)d_in[13];
    const float* bm   = (const float*)d_in[14];

    const long long MB = 1 << 20;
    char* W = (char*)d_ws;
    unsigned short* xq    = (unsigned short*)(W + 0*MB);
    unsigned short* xk    = (unsigned short*)(W + 4*MB);
    unsigned short* xv    = (unsigned short*)(W + 8*MB);
    unsigned short* Wqb   = (unsigned short*)(W + 12*MB);
    unsigned short* Wkb   = (unsigned short*)(W + 14*MB);
    unsigned short* Wvb   = (unsigned short*)(W + 16*MB);
    unsigned short* Wmb   = (unsigned short*)(W + 18*MB);
    unsigned short* qhb   = (unsigned short*)(W + 20*MB);
    unsigned short* khb   = (unsigned short*)(W + 24*MB);
    unsigned short* vht   = (unsigned short*)(W + 28*MB);
    unsigned short* atted = (unsigned short*)(W + 32*MB);
    unsigned short* biasT = (unsigned short*)(W + 36*MB);  // 32 MB

    convert_kernel<<<10240, 256, 0, stream>>>(q, k, v, Wq, Wk, Wv, Wm, (unsigned short*)W);

    Gemm3 gp;
    gp.j[0] = { xq, Wqb, bq, (char*)qhb, 2 };
    gp.j[1] = { xk, Wkb, bk, (char*)khb, 1 };
    gp.j[2] = { xv, Wvb, bv, (char*)vht, 3 };
    gemm_bt<<<dim3(32, 8, 3), 256, 0, stream>>>(gp);

    rel_kernel<<<dim3(8, 512, 4), 256, 0, stream>>>(rel, Wr, br, biasT);

    attn_kernel<<<dim3(32, 16, 4), 256, 0, stream>>>(qhb, khb, vht, biasT, mask, atted);

    Gemm3 gf;
    gf.j[0] = { atted, Wmb, bm, (char*)d_out, 0 };
    gf.j[1] = gf.j[0];
    gf.j[2] = gf.j[0];
    gemm_bt<<<dim3(32, 8, 1), 256, 0, stream>>>(gf);
}